// Round 13
// baseline (234.938 us; speedup 1.0000x reference)
//
#include <hip/hip_runtime.h>

#define N_NODES 100000
#define N_EDGES 1600000
#define F_INPUT 4
#define HDIM 64
#define G_GRAPHS 1000
#define C_CLS 3

#define NPB 256          // nodes per bucket (power of 2)
#define BSHIFT 8
#define NB 391           // ceil(N_NODES / NPB)
#define CBLK 98          // ceil(N_EDGES / 16384)
#define CSR_CAP 6144     // max edges per bucket staged in LDS
#define HIST_BLOCKS 512
#define BNDS_BLOCKS 391  // ceil(N / 256)

typedef __attribute__((ext_vector_type(8))) short bf16x8;
typedef __attribute__((ext_vector_type(4))) float f32x4;

__device__ __forceinline__ unsigned short f2bf(float f) {
    unsigned u = __float_as_uint(f);
    unsigned r = (u + 0x7FFF + ((u >> 16) & 1)) >> 16;  // round-to-nearest-even
    return (unsigned short)r;
}
__device__ __forceinline__ float bflo(unsigned u) {
    return __uint_as_float(u << 16);
}
__device__ __forceinline__ float bfhi(unsigned u) {
    return __uint_as_float(u & 0xFFFF0000u);
}
__device__ __forceinline__ float bf1(unsigned short s) {
    return __uint_as_float(((unsigned)s) << 16);
}

// ---------------- W' = W_emb @ W_l ; b' = b_emb @ W_l + b_l ; zero bcnt ----------------
__global__ __launch_bounds__(256) void k_prew(
    const float* __restrict__ w_emb, const float* __restrict__ b_emb,
    const float* __restrict__ lin1_w, const float* __restrict__ lin1_b,
    const float* __restrict__ lin2_w,
    const float* __restrict__ lin3_w, const float* __restrict__ lin3_b,
    float* __restrict__ wp, float* __restrict__ bp, int* __restrict__ bcnt) {
    int t = threadIdx.x;       // 256 = 4 * 64
    for (int i = t; i < NB; i += 256) bcnt[i] = 0;
    int k = t >> 6, f = t & 63;
    const float* Ws[3] = {lin1_w, lin2_w, lin3_w};
#pragma unroll
    for (int m = 0; m < 3; ++m) {
        float s = 0.f;
        for (int j = 0; j < HDIM; ++j) s += w_emb[k * HDIM + j] * Ws[m][j * HDIM + f];
        wp[m * 256 + k * HDIM + f] = s;
    }
    if (t < HDIM) {
#pragma unroll
        for (int m = 0; m < 3; ++m) {
            float s = 0.f;
            for (int j = 0; j < HDIM; ++j) s += b_emb[j] * Ws[m][j * HDIM + t];
            if (m == 0) s += lin1_b[t];
            if (m == 2) s += lin3_b[t];
            bp[m * HDIM + t] = s;
        }
    }
}

// ---------------- fused: bucket histogram + graph bounds ----------------
__global__ __launch_bounds__(256) void k_hist_bounds(
    const int* __restrict__ dst, int* __restrict__ bcnt,
    const int* __restrict__ batch, int* __restrict__ goff) {
    __shared__ int s[NB];
    if (blockIdx.x < HIST_BLOCKS) {
        int bb = blockIdx.x;
        for (int i = threadIdx.x; i < NB; i += 256) s[i] = 0;
        __syncthreads();
        for (int e = bb * 256 + threadIdx.x; e < N_EDGES; e += HIST_BLOCKS * 256)
            atomicAdd(&s[dst[e] >> BSHIFT], 1);
        __syncthreads();
        for (int i = threadIdx.x; i < NB; i += 256)
            if (s[i]) atomicAdd(&bcnt[i], s[i]);
    } else {
        int n = (blockIdx.x - HIST_BLOCKS) * 256 + threadIdx.x;
        if (n >= N_NODES) return;
        int bv = batch[n];
        int bp_ = (n == 0) ? -1 : batch[n - 1];
        for (int g = bp_ + 1; g <= bv; ++g) goff[g] = n;
        if (n == N_NODES - 1) {
            for (int g = bv + 1; g <= G_GRAPHS; ++g) goff[g] = N_NODES;
        }
    }
}

// ---------------- bucket-offset scan (1 block) ----------------
__global__ __launch_bounds__(512) void k_boff(
    const int* __restrict__ bcnt, int* __restrict__ boff, int* __restrict__ bcur) {
    __shared__ int s[512];
    int t = threadIdx.x;
    int v = (t < NB) ? bcnt[t] : 0;
    s[t] = v;
    __syncthreads();
    for (int d = 1; d < 512; d <<= 1) {
        int x2 = (t >= d) ? s[t - d] : 0;
        __syncthreads();
        s[t] += x2;
        __syncthreads();
    }
    int ex = s[t] - v;
    if (t < NB) { boff[t] = ex; bcur[t] = ex; }
    if (t == 0) boff[NB] = N_EDGES;
}

// ---------------- scatter edges into buckets (packed 8B records) ----------------
__global__ __launch_bounds__(1024) void k_bucket(const int* __restrict__ src,
                                                 const int* __restrict__ dst,
                                                 const float* __restrict__ attr,
                                                 int* __restrict__ bcur,
                                                 int2* __restrict__ bbuf) {
    __shared__ int cnt[NB];
    __shared__ int base[NB];
    for (int i = threadIdx.x; i < NB; i += 1024) cnt[i] = 0;
    __syncthreads();
    int e0 = blockIdx.x * 16384;
    int myb[16], myrank[16];
    int2 mypack[16];
#pragma unroll
    for (int k = 0; k < 16; ++k) {
        int e = e0 + k * 1024 + threadIdx.x;
        if (e < N_EDGES) {
            int d = dst[e];
            int b = d >> BSHIFT;
            myb[k] = b;
            myrank[k] = atomicAdd(&cnt[b], 1);
            mypack[k].x = src[e] | ((d & (NPB - 1)) << 17);
            mypack[k].y = __float_as_int(attr[e]);
        } else
            myb[k] = -1;
    }
    __syncthreads();
    for (int i = threadIdx.x; i < NB; i += 1024)
        base[i] = cnt[i] ? atomicAdd(&bcur[i], cnt[i]) : 0;
    __syncthreads();
#pragma unroll
    for (int k = 0; k < 16; ++k)
        if (myb[k] >= 0) bbuf[base[myb[k]] + myrank[k]] = mypack[k];
}

// ---------------- per-bucket CSR finalize + fused layer-0 3-GEMM ----------------
// Builds off/wsum/edge2 for its 256 nodes, then computes (from x, folded weights):
// a0 = x@W1'+b1' ; d0 = x@W3'+b3' - (x@W2'+b2')*wsum   using LDS wsm.
__global__ __launch_bounds__(256) void k_csr(const int2* __restrict__ bbuf,
                                             const int* __restrict__ boff,
                                             int* __restrict__ off,
                                             float* __restrict__ wsum,
                                             int2* __restrict__ edge2,
                                             const float* __restrict__ x,
                                             const float* __restrict__ wp,
                                             const float* __restrict__ bp,
                                             unsigned short* __restrict__ a_out,
                                             unsigned short* __restrict__ d_out_) {
    __shared__ int2 se[CSR_CAP];   // 48 KB
    __shared__ int deg[NPB];
    __shared__ float wsm[NPB];
    __shared__ int loff[NPB];
    __shared__ int sct[256];
    int b = blockIdx.x;
    int lo = boff[b];
    int cnt = boff[b + 1] - lo;
    if (cnt > CSR_CAP) cnt = CSR_CAP;   // statistically impossible; safety clamp
    int t = threadIdx.x;
    deg[t] = 0;
    wsm[t] = 0.f;
    for (int i = t; i < cnt; i += 256) se[i] = bbuf[lo + i];
    __syncthreads();
    for (int i = t; i < cnt; i += 256) {
        int2 p = se[i];
        int dloc = (p.x >> 17) & (NPB - 1);
        atomicAdd(&deg[dloc], 1);
        atomicAdd(&wsm[dloc], __int_as_float(p.y));
    }
    __syncthreads();
    int v = deg[t];
    sct[t] = v;
    __syncthreads();
    for (int d = 1; d < 256; d <<= 1) {
        int x2 = (t >= d) ? sct[t - d] : 0;
        __syncthreads();
        sct[t] += x2;
        __syncthreads();
    }
    int ex = sct[t] - v;
    loff[t] = ex;
    __syncthreads();
    int n0 = b * NPB + t;
    if (n0 < N_NODES) { off[n0] = lo + ex; wsum[n0] = wsm[t]; }
    if (b == NB - 1 && t == 0) off[N_NODES] = N_EDGES;
    deg[t] = 0;  // reuse as cursor
    __syncthreads();
    for (int i = t; i < cnt; i += 256) {
        int2 p = se[i];
        int dloc = (p.x >> 17) & (NPB - 1);
        int r = atomicAdd(&deg[dloc], 1);
        edge2[lo + loff[dloc] + r] = make_int2(p.x & 0x1FFFF, p.y);
    }

    // ---- fused layer-0 3-GEMM for this bucket's 256 nodes (K=4 folded) ----
    {
        int wave = t >> 6, lane = t & 63;
        int row = lane & 15, kg = lane >> 4;
        int col = wave * 16 + row;
        bf16x8 Bf[3];
#pragma unroll
        for (int m = 0; m < 3; ++m) {
            union { bf16x8 v; unsigned short u[8]; } fr;
#pragma unroll
            for (int j = 0; j < 8; ++j)
                fr.u[j] = (kg == 0 && j < F_INPUT) ? f2bf(wp[m * 256 + j * HDIM + col])
                                                   : (unsigned short)0;
            Bf[m] = fr.v;
        }
        float bias1 = bp[col], bias2 = bp[HDIM + col], bias3 = bp[2 * HDIM + col];
        int base = b * NPB;
        for (int tt = 0; tt < 16; ++tt) {
            int n = base + tt * 16 + row;
            union { bf16x8 v; unsigned short u[8]; } af;
#pragma unroll
            for (int j = 0; j < 8; ++j) af.u[j] = 0;
            if (kg == 0 && n < N_NODES) {
                float4 xv = *(const float4*)(x + (size_t)n * F_INPUT);
                af.u[0] = f2bf(xv.x); af.u[1] = f2bf(xv.y);
                af.u[2] = f2bf(xv.z); af.u[3] = f2bf(xv.w);
            }
            f32x4 ac0 = (f32x4){0.f, 0.f, 0.f, 0.f};
            f32x4 ac1 = (f32x4){0.f, 0.f, 0.f, 0.f};
            f32x4 ac2 = (f32x4){0.f, 0.f, 0.f, 0.f};
            ac0 = __builtin_amdgcn_mfma_f32_16x16x32_bf16(af.v, Bf[0], ac0, 0, 0, 0);
            ac1 = __builtin_amdgcn_mfma_f32_16x16x32_bf16(af.v, Bf[1], ac1, 0, 0, 0);
            ac2 = __builtin_amdgcn_mfma_f32_16x16x32_bf16(af.v, Bf[2], ac2, 0, 0, 0);
#pragma unroll
            for (int r = 0; r < 4; ++r) {
                int nn = base + tt * 16 + kg * 4 + r;
                if (nn >= N_NODES) continue;
                float ws = wsm[tt * 16 + kg * 4 + r];
                float av = ac0[r] + bias1;
                float dv = ac2[r] + bias3 - (ac1[r] + bias2) * ws;
                a_out[(size_t)nn * HDIM + col] = f2bf(av);
                d_out_[(size_t)nn * HDIM + col] = f2bf(dv);
            }
        }
    }
}

// ---------------- MFMA fused 3-GEMM layer-1 (h bf16 in; a bf16, d bf16 out) ----------------
__global__ __launch_bounds__(256) void k_gemm3(
    const unsigned short* __restrict__ h,
    const float* __restrict__ W1, const float* __restrict__ b1,
    const float* __restrict__ W2,
    const float* __restrict__ W3, const float* __restrict__ b3,
    const float* __restrict__ wsum,
    unsigned short* __restrict__ a_out, unsigned short* __restrict__ d_out_) {
    int wave = threadIdx.x >> 6;   // coltile 0..3
    int lane = threadIdx.x & 63;
    int row = lane & 15;
    int kg = lane >> 4;            // k-group 0..3
    int base = blockIdx.x * 64;
    int col = wave * 16 + row;     // output feature

    bf16x8 Bf[3][2];
    const float* Ws[3] = {W1, W2, W3};
#pragma unroll
    for (int m = 0; m < 3; ++m)
#pragma unroll
        for (int hf = 0; hf < 2; ++hf) {
            union { bf16x8 v; unsigned short u[8]; } fr;
#pragma unroll
            for (int j = 0; j < 8; ++j) {
                int k = hf * 32 + kg * 8 + j;
                fr.u[j] = f2bf(Ws[m][k * HDIM + col]);
            }
            Bf[m][hf] = fr.v;
        }

    float bias1 = b1[col];
    float bias3 = b3[col];

    f32x4 acc[3][4];
#pragma unroll
    for (int m = 0; m < 3; ++m)
#pragma unroll
        for (int t = 0; t < 4; ++t) acc[m][t] = (f32x4){0.f, 0.f, 0.f, 0.f};

#pragma unroll
    for (int t = 0; t < 4; ++t) {
        int n = base + t * 16 + row;
        bf16x8 a0, a1;
        if (n < N_NODES) {
            const unsigned short* hr = h + (size_t)n * HDIM;
            a0 = *(const bf16x8*)(hr + kg * 8);
            a1 = *(const bf16x8*)(hr + 32 + kg * 8);
        } else {
            a0 = (bf16x8){0,0,0,0,0,0,0,0};
            a1 = (bf16x8){0,0,0,0,0,0,0,0};
        }
#pragma unroll
        for (int m = 0; m < 3; ++m) {
            acc[m][t] = __builtin_amdgcn_mfma_f32_16x16x32_bf16(a0, Bf[m][0], acc[m][t], 0, 0, 0);
            acc[m][t] = __builtin_amdgcn_mfma_f32_16x16x32_bf16(a1, Bf[m][1], acc[m][t], 0, 0, 0);
        }
    }

#pragma unroll
    for (int t = 0; t < 4; ++t) {
#pragma unroll
        for (int r = 0; r < 4; ++r) {
            int n = base + t * 16 + kg * 4 + r;
            if (n >= N_NODES) continue;
            float ws = wsum[n];
            float av = acc[0][t][r] + bias1;
            float dv = acc[2][t][r] + bias3 - acc[1][t][r] * ws;
            a_out[(size_t)n * HDIM + col] = f2bf(av);
            d_out_[(size_t)n * HDIM + col] = f2bf(dv);
        }
    }
}

// ---------------- CSR aggregate + relu: h = relu(sum_j a[src_j]*w_j + d) ----------------
// 8 slots x 8 lanes; each lane gathers bf16x8 (16B), unroll x4 -> 32 edges/iter.
__global__ __launch_bounds__(256) void k_agg(const int2* __restrict__ edge2,
                                             const int* __restrict__ off,
                                             const unsigned short* __restrict__ a,
                                             const unsigned short* __restrict__ dbuf,
                                             unsigned short* __restrict__ h) {
    int wid = threadIdx.x >> 6;
    int lane = threadIdx.x & 63;
    int slot = lane >> 3;        // 0..7
    int fo = lane & 7;           // feature octet: feats [fo*8, fo*8+8)
    int n = blockIdx.x * 4 + wid;
    if (n >= N_NODES) return;
    int lo = off[n], hi = off[n + 1];

    float acc[8];
#pragma unroll
    for (int q = 0; q < 8; ++q) acc[q] = 0.f;

#define GATHER_ADD(J)                                                        \
    if ((J) < hi) {                                                          \
        int2 p = edge2[(J)];                                                 \
        float w = __int_as_float(p.y);                                       \
        uint4 u = *(const uint4*)(a + (size_t)p.x * HDIM + fo * 8);          \
        acc[0] += bflo(u.x) * w; acc[1] += bfhi(u.x) * w;                    \
        acc[2] += bflo(u.y) * w; acc[3] += bfhi(u.y) * w;                    \
        acc[4] += bflo(u.z) * w; acc[5] += bfhi(u.z) * w;                    \
        acc[6] += bflo(u.w) * w; acc[7] += bfhi(u.w) * w;                    \
    }

    for (int j0 = lo; j0 < hi; j0 += 32) {
        GATHER_ADD(j0 + slot)
        GATHER_ADD(j0 + 8 + slot)
        GATHER_ADD(j0 + 16 + slot)
        GATHER_ADD(j0 + 24 + slot)
    }
#undef GATHER_ADD

#pragma unroll
    for (int m = 8; m <= 32; m <<= 1) {
#pragma unroll
        for (int q = 0; q < 8; ++q) acc[q] += __shfl_xor(acc[q], m);
    }

    if (slot == 0) {
        size_t o = (size_t)n * HDIM + fo * 8;
        uint4 dv = *(const uint4*)(dbuf + o);
        float dd[8] = {bflo(dv.x), bfhi(dv.x), bflo(dv.y), bfhi(dv.y),
                       bflo(dv.z), bfhi(dv.z), bflo(dv.w), bfhi(dv.w)};
        unsigned r[4];
#pragma unroll
        for (int q = 0; q < 4; ++q) {
            unsigned lo16 = f2bf(fmaxf(acc[2 * q] + dd[2 * q], 0.f));
            unsigned hi16 = f2bf(fmaxf(acc[2 * q + 1] + dd[2 * q + 1], 0.f));
            r[q] = lo16 | (hi16 << 16);
        }
        *(uint4*)(h + o) = make_uint4(r[0], r[1], r[2], r[3]);
    }
}

// ---------------- fused mean pool + MLP head: one block per graph, 256 thr ----------------
__global__ __launch_bounds__(256) void k_poolhead(const unsigned short* __restrict__ h,
                                                  const int* __restrict__ goff,
                                                  const float* __restrict__ W1,
                                                  const float* __restrict__ b1,
                                                  const float* __restrict__ W2,
                                                  const float* __restrict__ b2,
                                                  float* __restrict__ out) {
    int g = blockIdx.x;
    __shared__ float part[256];
    __shared__ float sx[HDIM];
    __shared__ float sy[2 * HDIM];
    int t = threadIdx.x;
    int lo = goff[g], hi = goff[g + 1];
    int f = t & 63, quarter = t >> 6;
    float acc = 0.f;
    for (int n = lo + quarter; n < hi; n += 4) acc += bf1(h[(size_t)n * HDIM + f]);
    part[t] = acc;
    __syncthreads();
    if (t < HDIM)
        sx[t] = (part[t] + part[t + 64] + part[t + 128] + part[t + 192]) /
                fmaxf((float)(hi - lo), 1.f);
    __syncthreads();
    if (t < 2 * HDIM) {
        float a1 = b1[t];
        for (int k = 0; k < HDIM; ++k) a1 += sx[k] * W1[k * 2 * HDIM + t];
        sy[t] = fmaxf(a1, 0.f);
    }
    __syncthreads();
    if (t < C_CLS) {
        float o = b2[t];
        for (int k = 0; k < 2 * HDIM; ++k) o += sy[k] * W2[k * C_CLS + t];
        out[g * C_CLS + t] = o;
    }
}

extern "C" void kernel_launch(void* const* d_in, const int* in_sizes, int n_in,
                              void* d_out, int out_size, void* d_ws, size_t ws_size,
                              hipStream_t stream) {
    const float* x      = (const float*)d_in[0];
    const int*   ei     = (const int*)d_in[1];
    const float* eattr  = (const float*)d_in[2];
    const int*   batch  = (const int*)d_in[3];
    const float* w_emb  = (const float*)d_in[4];
    const float* b_emb  = (const float*)d_in[5];
    const float* lin1_w = (const float*)d_in[6];
    const float* lin1_b = (const float*)d_in[7];
    const float* lin2_w = (const float*)d_in[8];
    const float* lin3_w = (const float*)d_in[9];
    const float* lin3_b = (const float*)d_in[10];
    const float* mlp_w1 = (const float*)d_in[11];
    const float* mlp_b1 = (const float*)d_in[12];
    const float* mlp_w2 = (const float*)d_in[13];
    const float* mlp_b2 = (const float*)d_in[14];
    float* out = (float*)d_out;

    const int* src = ei;
    const int* dst = ei + N_EDGES;

    const size_t NH = (size_t)N_NODES * HDIM;
    unsigned short* abf = (unsigned short*)d_ws;     // NH bf16
    unsigned short* dbf = abf + NH;                  // NH bf16
    unsigned short* h   = dbf + NH;                  // NH bf16
    float* wsum = (float*)(h + NH);                  // N
    int2* edge2 = (int2*)(wsum + N_NODES);           // E
    int2* bbuf  = edge2 + N_EDGES;                   // E
    int* off    = (int*)(bbuf + N_EDGES);            // N+1
    int* bcnt   = off + N_NODES + 1;                 // NB
    int* bcur   = bcnt + NB;                         // NB
    int* boff   = bcur + NB;                         // NB+1
    int* goff   = boff + NB + 1;                     // G+1
    float* wp   = (float*)(goff + G_GRAPHS + 1);     // 3*4*64
    float* bp   = wp + 3 * 256;                      // 3*64

    k_prew<<<1, 256, 0, stream>>>(w_emb, b_emb,
                                  lin1_w, lin1_b, lin2_w, lin3_w, lin3_b, wp, bp, bcnt);
    k_hist_bounds<<<HIST_BLOCKS + BNDS_BLOCKS, 256, 0, stream>>>(dst, bcnt, batch, goff);
    k_boff<<<1, 512, 0, stream>>>(bcnt, boff, bcur);
    k_bucket<<<CBLK, 1024, 0, stream>>>(src, dst, eattr, bcur, bbuf);
    k_csr<<<NB, 256, 0, stream>>>(bbuf, boff, off, wsum, edge2, x, wp, bp, abf, dbf);

    int gemm_blocks = (N_NODES + 63) / 64;           // 1563
    int agg_blocks = (N_NODES + 3) / 4;              // 25000

    k_agg<<<agg_blocks, 256, 0, stream>>>(edge2, off, abf, dbf, h);
    k_gemm3<<<gemm_blocks, 256, 0, stream>>>(h, lin1_w + HDIM * HDIM, lin1_b + HDIM,
                                             lin2_w + HDIM * HDIM,
                                             lin3_w + HDIM * HDIM, lin3_b + HDIM,
                                             wsum, abf, dbf);
    k_agg<<<agg_blocks, 256, 0, stream>>>(edge2, off, abf, dbf, h);
    k_poolhead<<<G_GRAPHS, 256, 0, stream>>>(h, goff, mlp_w1, mlp_b1, mlp_w2, mlp_b2, out);
}

// Round 14
// 228.011 us; speedup vs baseline: 1.0304x; 1.0304x over previous
//
#include <hip/hip_runtime.h>

#define N_NODES 100000
#define N_EDGES 1600000
#define F_INPUT 4
#define HDIM 64
#define G_GRAPHS 1000
#define C_CLS 3

#define NPB 256          // nodes per bucket (power of 2)
#define BSHIFT 8
#define NB 391           // ceil(N_NODES / NPB)
#define CBLK 98          // ceil(N_EDGES / 16384)
#define CSR_CAP 6144     // max edges per bucket staged in LDS
#define HIST_BLOCKS 512
#define BNDS_BLOCKS 391  // ceil(N / 256)

typedef __attribute__((ext_vector_type(8))) short bf16x8;
typedef __attribute__((ext_vector_type(4))) float f32x4;

__device__ __forceinline__ unsigned short f2bf(float f) {
    unsigned u = __float_as_uint(f);
    unsigned r = (u + 0x7FFF + ((u >> 16) & 1)) >> 16;  // round-to-nearest-even
    return (unsigned short)r;
}
__device__ __forceinline__ float bflo(unsigned u) {
    return __uint_as_float(u << 16);
}
__device__ __forceinline__ float bfhi(unsigned u) {
    return __uint_as_float(u & 0xFFFF0000u);
}
__device__ __forceinline__ float bf1(unsigned short s) {
    return __uint_as_float(((unsigned)s) << 16);
}

// ---------------- W' = W_emb @ W_l ; b' = b_emb @ W_l + b_l ; zero bcnt ----------------
__global__ __launch_bounds__(256) void k_prew(
    const float* __restrict__ w_emb, const float* __restrict__ b_emb,
    const float* __restrict__ lin1_w, const float* __restrict__ lin1_b,
    const float* __restrict__ lin2_w,
    const float* __restrict__ lin3_w, const float* __restrict__ lin3_b,
    float* __restrict__ wp, float* __restrict__ bp, int* __restrict__ bcnt) {
    int t = threadIdx.x;       // 256 = 4 * 64
    for (int i = t; i < NB; i += 256) bcnt[i] = 0;
    int k = t >> 6, f = t & 63;
    const float* Ws[3] = {lin1_w, lin2_w, lin3_w};
#pragma unroll
    for (int m = 0; m < 3; ++m) {
        float s = 0.f;
        for (int j = 0; j < HDIM; ++j) s += w_emb[k * HDIM + j] * Ws[m][j * HDIM + f];
        wp[m * 256 + k * HDIM + f] = s;
    }
    if (t < HDIM) {
#pragma unroll
        for (int m = 0; m < 3; ++m) {
            float s = 0.f;
            for (int j = 0; j < HDIM; ++j) s += b_emb[j] * Ws[m][j * HDIM + t];
            if (m == 0) s += lin1_b[t];
            if (m == 2) s += lin3_b[t];
            bp[m * HDIM + t] = s;
        }
    }
}

// ---------------- fused: bucket histogram (int4 reads) + graph bounds ----------------
__global__ __launch_bounds__(256) void k_hist_bounds(
    const int* __restrict__ dst, int* __restrict__ bcnt,
    const int* __restrict__ batch, int* __restrict__ goff) {
    __shared__ int s[NB];
    if (blockIdx.x < HIST_BLOCKS) {
        int bb = blockIdx.x;
        for (int i = threadIdx.x; i < NB; i += 256) s[i] = 0;
        __syncthreads();
        const int4* dst4 = (const int4*)dst;
        for (int e4 = bb * 256 + threadIdx.x; e4 < N_EDGES / 4; e4 += HIST_BLOCKS * 256) {
            int4 d = dst4[e4];
            atomicAdd(&s[d.x >> BSHIFT], 1);
            atomicAdd(&s[d.y >> BSHIFT], 1);
            atomicAdd(&s[d.z >> BSHIFT], 1);
            atomicAdd(&s[d.w >> BSHIFT], 1);
        }
        __syncthreads();
        for (int i = threadIdx.x; i < NB; i += 256)
            if (s[i]) atomicAdd(&bcnt[i], s[i]);
    } else {
        int n = (blockIdx.x - HIST_BLOCKS) * 256 + threadIdx.x;
        if (n >= N_NODES) return;
        int bv = batch[n];
        int bp_ = (n == 0) ? -1 : batch[n - 1];
        for (int g = bp_ + 1; g <= bv; ++g) goff[g] = n;
        if (n == N_NODES - 1) {
            for (int g = bv + 1; g <= G_GRAPHS; ++g) goff[g] = N_NODES;
        }
    }
}

// ---------------- bucket-offset scan (1 block) ----------------
__global__ __launch_bounds__(512) void k_boff(
    const int* __restrict__ bcnt, int* __restrict__ boff, int* __restrict__ bcur) {
    __shared__ int s[512];
    int t = threadIdx.x;
    int v = (t < NB) ? bcnt[t] : 0;
    s[t] = v;
    __syncthreads();
    for (int d = 1; d < 512; d <<= 1) {
        int x2 = (t >= d) ? s[t - d] : 0;
        __syncthreads();
        s[t] += x2;
        __syncthreads();
    }
    int ex = s[t] - v;
    if (t < NB) { boff[t] = ex; bcur[t] = ex; }
    if (t == 0) boff[NB] = N_EDGES;
}

// ---------------- scatter edges into buckets (packed 8B records) ----------------
__global__ __launch_bounds__(1024) void k_bucket(const int* __restrict__ src,
                                                 const int* __restrict__ dst,
                                                 const float* __restrict__ attr,
                                                 int* __restrict__ bcur,
                                                 int2* __restrict__ bbuf) {
    __shared__ int cnt[NB];
    __shared__ int base[NB];
    for (int i = threadIdx.x; i < NB; i += 1024) cnt[i] = 0;
    __syncthreads();
    int e0 = blockIdx.x * 16384;
    int myb[16], myrank[16];
    int2 mypack[16];
#pragma unroll
    for (int k = 0; k < 16; ++k) {
        int e = e0 + k * 1024 + threadIdx.x;
        if (e < N_EDGES) {
            int d = dst[e];
            int b = d >> BSHIFT;
            myb[k] = b;
            myrank[k] = atomicAdd(&cnt[b], 1);
            mypack[k].x = src[e] | ((d & (NPB - 1)) << 17);
            mypack[k].y = __float_as_int(attr[e]);
        } else
            myb[k] = -1;
    }
    __syncthreads();
    for (int i = threadIdx.x; i < NB; i += 1024)
        base[i] = cnt[i] ? atomicAdd(&bcur[i], cnt[i]) : 0;
    __syncthreads();
#pragma unroll
    for (int k = 0; k < 16; ++k)
        if (myb[k] >= 0) bbuf[base[myb[k]] + myrank[k]] = mypack[k];
}

// ---------------- per-bucket CSR finalize (single pass, LDS-staged) ----------------
__global__ __launch_bounds__(256) void k_csr(const int2* __restrict__ bbuf,
                                             const int* __restrict__ boff,
                                             int* __restrict__ off,
                                             float* __restrict__ wsum,
                                             int2* __restrict__ edge2) {
    __shared__ int2 se[CSR_CAP];   // 48 KB
    __shared__ int deg[NPB];
    __shared__ float wsm[NPB];
    __shared__ int loff[NPB];
    __shared__ int sct[256];
    int b = blockIdx.x;
    int lo = boff[b];
    int cnt = boff[b + 1] - lo;
    if (cnt > CSR_CAP) cnt = CSR_CAP;   // statistically impossible; safety clamp
    int t = threadIdx.x;
    deg[t] = 0;
    wsm[t] = 0.f;
    for (int i = t; i < cnt; i += 256) se[i] = bbuf[lo + i];
    __syncthreads();
    for (int i = t; i < cnt; i += 256) {
        int2 p = se[i];
        int dloc = (p.x >> 17) & (NPB - 1);
        atomicAdd(&deg[dloc], 1);
        atomicAdd(&wsm[dloc], __int_as_float(p.y));
    }
    __syncthreads();
    int v = deg[t];
    sct[t] = v;
    __syncthreads();
    for (int d = 1; d < 256; d <<= 1) {
        int x2 = (t >= d) ? sct[t - d] : 0;
        __syncthreads();
        sct[t] += x2;
        __syncthreads();
    }
    int ex = sct[t] - v;
    loff[t] = ex;
    __syncthreads();
    int n = b * NPB + t;
    if (n < N_NODES) { off[n] = lo + ex; wsum[n] = wsm[t]; }
    if (b == NB - 1 && t == 0) off[N_NODES] = N_EDGES;
    deg[t] = 0;  // reuse as cursor
    __syncthreads();
    for (int i = t; i < cnt; i += 256) {
        int2 p = se[i];
        int dloc = (p.x >> 17) & (NPB - 1);
        int r = atomicAdd(&deg[dloc], 1);
        edge2[lo + loff[dloc] + r] = make_int2(p.x & 0x1FFFF, p.y);
    }
}

// ---------------- layer-0 3-GEMM direct from x (K=4 via folded weights) ----------------
// a0 = x@W1' + b1' ; d0 = x@W3' + b3' - (x@W2' + b2')*wsum
__global__ __launch_bounds__(256) void k_gemm1st(
    const float* __restrict__ x, const float* __restrict__ wp,
    const float* __restrict__ bp, const float* __restrict__ wsum,
    unsigned short* __restrict__ a_out, unsigned short* __restrict__ d_out_) {
    int wave = threadIdx.x >> 6;
    int lane = threadIdx.x & 63;
    int row = lane & 15;
    int kg = lane >> 4;
    int base = blockIdx.x * 64;
    int col = wave * 16 + row;

    bf16x8 Bf[3];
#pragma unroll
    for (int m = 0; m < 3; ++m) {
        union { bf16x8 v; unsigned short u[8]; } fr;
#pragma unroll
        for (int j = 0; j < 8; ++j)
            fr.u[j] = (kg == 0 && j < F_INPUT) ? f2bf(wp[m * 256 + j * HDIM + col])
                                               : (unsigned short)0;
        Bf[m] = fr.v;
    }
    float bias1 = bp[col], bias2 = bp[HDIM + col], bias3 = bp[2 * HDIM + col];

    f32x4 acc[3][4];
#pragma unroll
    for (int m = 0; m < 3; ++m)
#pragma unroll
        for (int t = 0; t < 4; ++t) acc[m][t] = (f32x4){0.f, 0.f, 0.f, 0.f};

#pragma unroll
    for (int t = 0; t < 4; ++t) {
        int n = base + t * 16 + row;
        union { bf16x8 v; unsigned short u[8]; } af;
#pragma unroll
        for (int j = 0; j < 8; ++j) af.u[j] = 0;
        if (kg == 0 && n < N_NODES) {
            float4 xv = *(const float4*)(x + (size_t)n * F_INPUT);
            af.u[0] = f2bf(xv.x); af.u[1] = f2bf(xv.y);
            af.u[2] = f2bf(xv.z); af.u[3] = f2bf(xv.w);
        }
#pragma unroll
        for (int m = 0; m < 3; ++m)
            acc[m][t] = __builtin_amdgcn_mfma_f32_16x16x32_bf16(af.v, Bf[m], acc[m][t], 0, 0, 0);
    }

#pragma unroll
    for (int t = 0; t < 4; ++t) {
#pragma unroll
        for (int r = 0; r < 4; ++r) {
            int n = base + t * 16 + kg * 4 + r;
            if (n >= N_NODES) continue;
            float ws = wsum[n];
            float av = acc[0][t][r] + bias1;
            float dv = acc[2][t][r] + bias3 - (acc[1][t][r] + bias2) * ws;
            a_out[(size_t)n * HDIM + col] = f2bf(av);
            d_out_[(size_t)n * HDIM + col] = f2bf(dv);
        }
    }
}

// ---------------- MFMA fused 3-GEMM layer-1 (h bf16 in; a bf16, d bf16 out) ----------------
__global__ __launch_bounds__(256) void k_gemm3(
    const unsigned short* __restrict__ h,
    const float* __restrict__ W1, const float* __restrict__ b1,
    const float* __restrict__ W2,
    const float* __restrict__ W3, const float* __restrict__ b3,
    const float* __restrict__ wsum,
    unsigned short* __restrict__ a_out, unsigned short* __restrict__ d_out_) {
    int wave = threadIdx.x >> 6;   // coltile 0..3
    int lane = threadIdx.x & 63;
    int row = lane & 15;
    int kg = lane >> 4;            // k-group 0..3
    int base = blockIdx.x * 64;
    int col = wave * 16 + row;     // output feature

    bf16x8 Bf[3][2];
    const float* Ws[3] = {W1, W2, W3};
#pragma unroll
    for (int m = 0; m < 3; ++m)
#pragma unroll
        for (int hf = 0; hf < 2; ++hf) {
            union { bf16x8 v; unsigned short u[8]; } fr;
#pragma unroll
            for (int j = 0; j < 8; ++j) {
                int k = hf * 32 + kg * 8 + j;
                fr.u[j] = f2bf(Ws[m][k * HDIM + col]);
            }
            Bf[m][hf] = fr.v;
        }

    float bias1 = b1[col];
    float bias3 = b3[col];

    f32x4 acc[3][4];
#pragma unroll
    for (int m = 0; m < 3; ++m)
#pragma unroll
        for (int t = 0; t < 4; ++t) acc[m][t] = (f32x4){0.f, 0.f, 0.f, 0.f};

#pragma unroll
    for (int t = 0; t < 4; ++t) {
        int n = base + t * 16 + row;
        bf16x8 a0, a1;
        if (n < N_NODES) {
            const unsigned short* hr = h + (size_t)n * HDIM;
            a0 = *(const bf16x8*)(hr + kg * 8);
            a1 = *(const bf16x8*)(hr + 32 + kg * 8);
        } else {
            a0 = (bf16x8){0,0,0,0,0,0,0,0};
            a1 = (bf16x8){0,0,0,0,0,0,0,0};
        }
#pragma unroll
        for (int m = 0; m < 3; ++m) {
            acc[m][t] = __builtin_amdgcn_mfma_f32_16x16x32_bf16(a0, Bf[m][0], acc[m][t], 0, 0, 0);
            acc[m][t] = __builtin_amdgcn_mfma_f32_16x16x32_bf16(a1, Bf[m][1], acc[m][t], 0, 0, 0);
        }
    }

#pragma unroll
    for (int t = 0; t < 4; ++t) {
#pragma unroll
        for (int r = 0; r < 4; ++r) {
            int n = base + t * 16 + kg * 4 + r;
            if (n >= N_NODES) continue;
            float ws = wsum[n];
            float av = acc[0][t][r] + bias1;
            float dv = acc[2][t][r] + bias3 - acc[1][t][r] * ws;
            a_out[(size_t)n * HDIM + col] = f2bf(av);
            d_out_[(size_t)n * HDIM + col] = f2bf(dv);
        }
    }
}

// ---------------- CSR aggregate + relu: h = relu(sum_j a[src_j]*w_j + d) ----------------
// 8 slots x 8 lanes; each lane gathers bf16x8 (16B), unroll x4 -> 32 edges/iter.
__global__ __launch_bounds__(256) void k_agg(const int2* __restrict__ edge2,
                                             const int* __restrict__ off,
                                             const unsigned short* __restrict__ a,
                                             const unsigned short* __restrict__ dbuf,
                                             unsigned short* __restrict__ h) {
    int wid = threadIdx.x >> 6;
    int lane = threadIdx.x & 63;
    int slot = lane >> 3;        // 0..7
    int fo = lane & 7;           // feature octet: feats [fo*8, fo*8+8)
    int n = blockIdx.x * 4 + wid;
    if (n >= N_NODES) return;
    int lo = off[n], hi = off[n + 1];

    float acc[8];
#pragma unroll
    for (int q = 0; q < 8; ++q) acc[q] = 0.f;

#define GATHER_ADD(J)                                                        \
    if ((J) < hi) {                                                          \
        int2 p = edge2[(J)];                                                 \
        float w = __int_as_float(p.y);                                       \
        uint4 u = *(const uint4*)(a + (size_t)p.x * HDIM + fo * 8);          \
        acc[0] += bflo(u.x) * w; acc[1] += bfhi(u.x) * w;                    \
        acc[2] += bflo(u.y) * w; acc[3] += bfhi(u.y) * w;                    \
        acc[4] += bflo(u.z) * w; acc[5] += bfhi(u.z) * w;                    \
        acc[6] += bflo(u.w) * w; acc[7] += bfhi(u.w) * w;                    \
    }

    for (int j0 = lo; j0 < hi; j0 += 32) {
        GATHER_ADD(j0 + slot)
        GATHER_ADD(j0 + 8 + slot)
        GATHER_ADD(j0 + 16 + slot)
        GATHER_ADD(j0 + 24 + slot)
    }
#undef GATHER_ADD

#pragma unroll
    for (int m = 8; m <= 32; m <<= 1) {
#pragma unroll
        for (int q = 0; q < 8; ++q) acc[q] += __shfl_xor(acc[q], m);
    }

    if (slot == 0) {
        size_t o = (size_t)n * HDIM + fo * 8;
        uint4 dv = *(const uint4*)(dbuf + o);
        float dd[8] = {bflo(dv.x), bfhi(dv.x), bflo(dv.y), bfhi(dv.y),
                       bflo(dv.z), bfhi(dv.z), bflo(dv.w), bfhi(dv.w)};
        unsigned r[4];
#pragma unroll
        for (int q = 0; q < 4; ++q) {
            unsigned lo16 = f2bf(fmaxf(acc[2 * q] + dd[2 * q], 0.f));
            unsigned hi16 = f2bf(fmaxf(acc[2 * q + 1] + dd[2 * q + 1], 0.f));
            r[q] = lo16 | (hi16 << 16);
        }
        *(uint4*)(h + o) = make_uint4(r[0], r[1], r[2], r[3]);
    }
}

// ---------------- fused mean pool + MLP head: one block per graph, 256 thr ----------------
__global__ __launch_bounds__(256) void k_poolhead(const unsigned short* __restrict__ h,
                                                  const int* __restrict__ goff,
                                                  const float* __restrict__ W1,
                                                  const float* __restrict__ b1,
                                                  const float* __restrict__ W2,
                                                  const float* __restrict__ b2,
                                                  float* __restrict__ out) {
    int g = blockIdx.x;
    __shared__ float part[256];
    __shared__ float sx[HDIM];
    __shared__ float sy[2 * HDIM];
    int t = threadIdx.x;
    int lo = goff[g], hi = goff[g + 1];
    int f = t & 63, quarter = t >> 6;
    float acc = 0.f;
    for (int n = lo + quarter; n < hi; n += 4) acc += bf1(h[(size_t)n * HDIM + f]);
    part[t] = acc;
    __syncthreads();
    if (t < HDIM)
        sx[t] = (part[t] + part[t + 64] + part[t + 128] + part[t + 192]) /
                fmaxf((float)(hi - lo), 1.f);
    __syncthreads();
    if (t < 2 * HDIM) {
        float a1 = b1[t];
        for (int k = 0; k < HDIM; ++k) a1 += sx[k] * W1[k * 2 * HDIM + t];
        sy[t] = fmaxf(a1, 0.f);
    }
    __syncthreads();
    if (t < C_CLS) {
        float o = b2[t];
        for (int k = 0; k < 2 * HDIM; ++k) o += sy[k] * W2[k * C_CLS + t];
        out[g * C_CLS + t] = o;
    }
}

extern "C" void kernel_launch(void* const* d_in, const int* in_sizes, int n_in,
                              void* d_out, int out_size, void* d_ws, size_t ws_size,
                              hipStream_t stream) {
    const float* x      = (const float*)d_in[0];
    const int*   ei     = (const int*)d_in[1];
    const float* eattr  = (const float*)d_in[2];
    const int*   batch  = (const int*)d_in[3];
    const float* w_emb  = (const float*)d_in[4];
    const float* b_emb  = (const float*)d_in[5];
    const float* lin1_w = (const float*)d_in[6];
    const float* lin1_b = (const float*)d_in[7];
    const float* lin2_w = (const float*)d_in[8];
    const float* lin3_w = (const float*)d_in[9];
    const float* lin3_b = (const float*)d_in[10];
    const float* mlp_w1 = (const float*)d_in[11];
    const float* mlp_b1 = (const float*)d_in[12];
    const float* mlp_w2 = (const float*)d_in[13];
    const float* mlp_b2 = (const float*)d_in[14];
    float* out = (float*)d_out;

    const int* src = ei;
    const int* dst = ei + N_EDGES;

    const size_t NH = (size_t)N_NODES * HDIM;
    unsigned short* abf = (unsigned short*)d_ws;     // NH bf16
    unsigned short* dbf = abf + NH;                  // NH bf16
    unsigned short* h   = dbf + NH;                  // NH bf16
    float* wsum = (float*)(h + NH);                  // N
    int2* edge2 = (int2*)(wsum + N_NODES);           // E
    int2* bbuf  = edge2 + N_EDGES;                   // E
    int* off    = (int*)(bbuf + N_EDGES);            // N+1
    int* bcnt   = off + N_NODES + 1;                 // NB
    int* bcur   = bcnt + NB;                         // NB
    int* boff   = bcur + NB;                         // NB+1
    int* goff   = boff + NB + 1;                     // G+1
    float* wp   = (float*)(goff + G_GRAPHS + 1);     // 3*4*64
    float* bp   = wp + 3 * 256;                      // 3*64

    k_prew<<<1, 256, 0, stream>>>(w_emb, b_emb,
                                  lin1_w, lin1_b, lin2_w, lin3_w, lin3_b, wp, bp, bcnt);
    k_hist_bounds<<<HIST_BLOCKS + BNDS_BLOCKS, 256, 0, stream>>>(dst, bcnt, batch, goff);
    k_boff<<<1, 512, 0, stream>>>(bcnt, boff, bcur);
    k_bucket<<<CBLK, 1024, 0, stream>>>(src, dst, eattr, bcur, bbuf);
    k_csr<<<NB, 256, 0, stream>>>(bbuf, boff, off, wsum, edge2);

    int gemm_blocks = (N_NODES + 63) / 64;           // 1563
    int agg_blocks = (N_NODES + 3) / 4;              // 25000

    k_gemm1st<<<gemm_blocks, 256, 0, stream>>>(x, wp, bp, wsum, abf, dbf);
    k_agg<<<agg_blocks, 256, 0, stream>>>(edge2, off, abf, dbf, h);
    k_gemm3<<<gemm_blocks, 256, 0, stream>>>(h, lin1_w + HDIM * HDIM, lin1_b + HDIM,
                                             lin2_w + HDIM * HDIM,
                                             lin3_w + HDIM * HDIM, lin3_b + HDIM,
                                             wsum, abf, dbf);
    k_agg<<<agg_blocks, 256, 0, stream>>>(edge2, off, abf, dbf, h);
    k_poolhead<<<G_GRAPHS, 256, 0, stream>>>(h, goff, mlp_w1, mlp_b1, mlp_w2, mlp_b2, out);
}